// Round 1
// baseline (207.689 us; speedup 1.0000x reference)
//
#include <hip/hip_runtime.h>

#define IMG_H 480
#define IMG_W 640
#define OUT_H (IMG_H - 10)   // 470
#define OUT_W (IMG_W - 10)   // 630
#define NBATCH 32
#define TX 64
#define TY 16
#define IX (TX + 10)         // 74
#define IY (TY + 10)         // 26
#define WS 11

// SSIM constants: L = 100 -> C1 = (0.01*100)^2 = 1, C2 = (0.03*100)^2 = 9
#define SSIM_C1 1.0f
#define SSIM_C2 9.0f

__global__ __launch_bounds__(256) void ssim_tile_kernel(
    const float* __restrict__ img1,
    const float* __restrict__ img2,
    float* __restrict__ partials)
{
    const int tx0 = blockIdx.x * TX;
    const int ty0 = blockIdx.y * TY;
    const int b   = blockIdx.z;
    const int tid = threadIdx.x;

    // Gaussian 1D window in registers (matches numpy float32 computation)
    float w[WS];
    {
        float s = 0.f;
#pragma unroll
        for (int i = 0; i < WS; ++i) {
            float d = (float)(i - WS / 2);
            w[i] = expf(-(d * d) / (2.0f * 1.5f * 1.5f));
            s += w[i];
        }
        float inv = 1.0f / s;
#pragma unroll
        for (int i = 0; i < WS; ++i) w[i] *= inv;
    }

    __shared__ float s1[IY][IX];
    __shared__ float s2[IY][IX];
    __shared__ float h1[IY][TX];
    __shared__ float h2[IY][TX];
    __shared__ float h11[IY][TX];
    __shared__ float h22[IY][TX];
    __shared__ float h12[IY][TX];

    const float* p1 = img1 + (size_t)b * IMG_H * IMG_W;
    const float* p2 = img2 + (size_t)b * IMG_H * IMG_W;

    // Stage input tiles (with halo) into LDS; OOB -> 0 (only feeds invalid outputs)
    for (int idx = tid; idx < IY * IX; idx += 256) {
        int r = idx / IX, c = idx % IX;
        int gy = ty0 + r, gx = tx0 + c;
        float v1 = 0.f, v2 = 0.f;
        if (gy < IMG_H && gx < IMG_W) {
            int g = gy * IMG_W + gx;
            v1 = p1[g];
            v2 = p2[g];
        }
        s1[r][c] = v1;
        s2[r][c] = v2;
    }
    __syncthreads();

    // Horizontal 11-tap pass for 5 channels (I1, I2, I1^2, I2^2, I1*I2)
    for (int idx = tid; idx < IY * TX; idx += 256) {
        int r = idx / TX, c = idx % TX;
        float a1 = 0.f, a2 = 0.f, a11 = 0.f, a22 = 0.f, a12 = 0.f;
#pragma unroll
        for (int j = 0; j < WS; ++j) {
            float v1 = s1[r][c + j];
            float v2 = s2[r][c + j];
            float wj = w[j];
            a1  += wj * v1;
            a2  += wj * v2;
            a11 += wj * v1 * v1;
            a22 += wj * v2 * v2;
            a12 += wj * v1 * v2;
        }
        h1[r][c]  = a1;
        h2[r][c]  = a2;
        h11[r][c] = a11;
        h22[r][c] = a22;
        h12[r][c] = a12;
    }
    __syncthreads();

    // Vertical 11-tap pass + SSIM map + thread-local accumulation
    float acc = 0.f;
    for (int idx = tid; idx < TY * TX; idx += 256) {
        int y = idx / TX, x = idx % TX;
        int gy = ty0 + y, gx = tx0 + x;
        if (gy < OUT_H && gx < OUT_W) {
            float m1 = 0.f, m2 = 0.f, x11 = 0.f, x22 = 0.f, x12 = 0.f;
#pragma unroll
            for (int i = 0; i < WS; ++i) {
                float wi = w[i];
                m1  += wi * h1[y + i][x];
                m2  += wi * h2[y + i][x];
                x11 += wi * h11[y + i][x];
                x22 += wi * h22[y + i][x];
                x12 += wi * h12[y + i][x];
            }
            float mu1s = m1 * m1;
            float mu2s = m2 * m2;
            float mu12 = m1 * m2;
            float sg1  = x11 - mu1s;
            float sg2  = x22 - mu2s;
            float sg12 = x12 - mu12;
            float v1 = 2.0f * sg12 + SSIM_C2;
            float v2 = sg1 + sg2 + SSIM_C2;
            float num = (2.0f * mu12 + SSIM_C1) * v1;
            float den = (mu1s + mu2s + SSIM_C1) * v2;
            acc += num / den;
        }
    }

    // Block tree-reduce
    __shared__ float red[256];
    red[tid] = acc;
    __syncthreads();
    for (int s = 128; s > 0; s >>= 1) {
        if (tid < s) red[tid] += red[tid + s];
        __syncthreads();
    }
    if (tid == 0) {
        int bidx = (blockIdx.z * gridDim.y + blockIdx.y) * gridDim.x + blockIdx.x;
        partials[bidx] = red[0];
    }
}

__global__ __launch_bounds__(256) void ssim_reduce_kernel(
    const float* __restrict__ partials, int n, float* __restrict__ out)
{
    __shared__ double red[256];
    int tid = threadIdx.x;
    double s = 0.0;
    for (int i = tid; i < n; i += 256) s += (double)partials[i];
    red[tid] = s;
    __syncthreads();
    for (int k = 128; k > 0; k >>= 1) {
        if (tid < k) red[tid] += red[tid + k];
        __syncthreads();
    }
    if (tid == 0) {
        double mean = red[0] / (double)((size_t)NBATCH * OUT_H * OUT_W);
        out[0] = (float)((1.0 - mean) * 0.5);
    }
}

extern "C" void kernel_launch(void* const* d_in, const int* in_sizes, int n_in,
                              void* d_out, int out_size, void* d_ws, size_t ws_size,
                              hipStream_t stream)
{
    const float* img1 = (const float*)d_in[0];
    const float* img2 = (const float*)d_in[1];
    float* out = (float*)d_out;
    float* partials = (float*)d_ws;  // 9600 floats = 38.4 KB << ws_size

    dim3 grid((OUT_W + TX - 1) / TX, (OUT_H + TY - 1) / TY, NBATCH);  // 10 x 30 x 32
    ssim_tile_kernel<<<grid, dim3(256), 0, stream>>>(img1, img2, partials);

    int n = grid.x * grid.y * grid.z;
    ssim_reduce_kernel<<<1, dim3(256), 0, stream>>>(partials, n, out);
}

// Round 2
// 167.702 us; speedup vs baseline: 1.2384x; 1.2384x over previous
//
#include <hip/hip_runtime.h>

#define IMG_H 480
#define IMG_W 640
#define OUT_H 470    // 480 - 10
#define OUT_W 630    // 640 - 10
#define NBATCH 32
#define SW 54        // output columns per 64-lane wave (64 input cols - 10 halo)
#define NSTRIPE 12   // ceil(630 / 54)
#define RCH 59       // output rows per chunk
#define NCHUNK 8     // ceil(470 / 59)

#define SSIM_C1 1.0f // (0.01*100)^2
#define SSIM_C2 9.0f // (0.03*100)^2

// Normalized 11-tap Gaussian (sigma=1.5), matches numpy fp32 window to ~1e-7 rel.
__device__ constexpr float WG[11] = {
    0.00102838f, 0.00759876f, 0.03600077f, 0.10936068f, 0.21300554f,
    0.26601173f,
    0.21300554f, 0.10936068f, 0.03600077f, 0.00759876f, 0.00102838f
};

// One phase of the 11-deep vertical ring. P must be a compile-time constant
// after unrolling so all acc[] indices and weight selects fold to literals.
#define PHASE(P, IT)                                                          \
  {                                                                           \
    const int it = (IT);                                                      \
    int gy = y0 + it; if (gy > IMG_H - 1) gy = IMG_H - 1;                     \
    const float* __restrict__ r1 = p1 + gy * IMG_W;                           \
    const float* __restrict__ r2 = p2 + gy * IMG_W;                           \
    float a1 = r1[colA], a2 = r2[colA];                                       \
    float b1 = 0.f, b2 = 0.f;                                                 \
    if (lane < 10) { b1 = r1[colB]; b2 = r2[colB]; }                          \
    __syncthreads();                                                          \
    s1[lane] = a1; s2[lane] = a2;                                             \
    if (lane < 10) { s1[64 + lane] = b1; s2[64 + lane] = b2; }                \
    __syncthreads();                                                          \
    /* horizontal 11-tap pass, 5 channels, all in registers */                \
    float h1 = 0.f, h2 = 0.f, h11 = 0.f, h22 = 0.f, h12 = 0.f;                \
    _Pragma("unroll")                                                         \
    for (int j = 0; j < 11; ++j) {                                            \
      float v1 = s1[lane + j], v2 = s2[lane + j];                             \
      float t1 = WG[j] * v1, t2 = WG[j] * v2;                                 \
      h1 += t1; h2 += t2;                                                     \
      h11 = fmaf(t1, v1, h11);                                                \
      h22 = fmaf(t2, v2, h22);                                                \
      h12 = fmaf(t1, v2, h12);                                                \
    }                                                                         \
    /* vertical ring update: slot sl holds output row with y%11==sl */        \
    _Pragma("unroll")                                                         \
    for (int sl = 0; sl < 11; ++sl) {                                         \
      const float wt = WG[((P) - sl + 11) % 11];                              \
      acc[sl][0] = fmaf(wt, h1,  acc[sl][0]);                                 \
      acc[sl][1] = fmaf(wt, h2,  acc[sl][1]);                                 \
      acc[sl][2] = fmaf(wt, h11, acc[sl][2]);                                 \
      acc[sl][3] = fmaf(wt, h22, acc[sl][3]);                                 \
      acc[sl][4] = fmaf(wt, h12, acc[sl][4]);                                 \
    }                                                                         \
    /* slot sc just received its w[10] tap -> output row y completes */       \
    const int sc = ((P) + 1) % 11;                                            \
    const int y = it - 10;                                                    \
    if (it >= 10 && y < RCH && (y0 + y) < OUT_H && valid_col) {               \
      float m1 = acc[sc][0], m2 = acc[sc][1];                                 \
      float mu1s = m1 * m1, mu2s = m2 * m2, mu12 = m1 * m2;                   \
      float vA = 2.f * (acc[sc][4] - mu12) + SSIM_C2;                         \
      float vB = (acc[sc][2] - mu1s) + (acc[sc][3] - mu2s) + SSIM_C2;         \
      float num = (2.f * mu12 + SSIM_C1) * vA;                                \
      float den = (mu1s + mu2s + SSIM_C1) * vB;                               \
      lsum += num / den;                                                      \
    }                                                                         \
    acc[sc][0] = 0.f; acc[sc][1] = 0.f; acc[sc][2] = 0.f;                     \
    acc[sc][3] = 0.f; acc[sc][4] = 0.f;                                       \
  }

__global__ __launch_bounds__(64, 4) void ssim_main(
    const float* __restrict__ img1,
    const float* __restrict__ img2,
    float* __restrict__ partials)
{
    const int lane   = threadIdx.x;
    const int stripe = blockIdx.x;
    const int cy     = blockIdx.y;
    const int b      = blockIdx.z;
    const int x0 = SW * stripe;
    const int y0 = RCH * cy;

    __shared__ float s1[76], s2[76];

    const float* __restrict__ p1 = img1 + (size_t)b * (IMG_H * IMG_W);
    const float* __restrict__ p2 = img2 + (size_t)b * (IMG_H * IMG_W);

    int colA = x0 + lane;        if (colA > IMG_W - 1) colA = IMG_W - 1;
    int colB = x0 + 64 + lane;   if (colB > IMG_W - 1) colB = IMG_W - 1;

    const bool valid_col = (lane < SW) && (x0 + lane < OUT_W);

    float acc[11][5];
#pragma unroll
    for (int i = 0; i < 11; ++i)
#pragma unroll
        for (int j = 0; j < 5; ++j) acc[i][j] = 0.f;

    float lsum = 0.f;

    // 69 input rows: 6 full 11-phase blocks + 3 tail phases
    for (int blk = 0; blk < 6; ++blk) {
        const int base = blk * 11;
#pragma unroll
        for (int p = 0; p < 11; ++p) PHASE(p, base + p)
    }
    {
        const int base = 66;
#pragma unroll
        for (int p = 0; p < 3; ++p) PHASE(p, base + p)
    }

    // wave-level reduction (64 lanes)
#pragma unroll
    for (int off = 32; off > 0; off >>= 1)
        lsum += __shfl_down(lsum, off);
    if (lane == 0)
        partials[(b * NCHUNK + cy) * NSTRIPE + stripe] = lsum;
}

__global__ __launch_bounds__(256) void ssim_reduce(
    const float* __restrict__ partials, float* __restrict__ out)
{
    const int n = NSTRIPE * NCHUNK * NBATCH;  // 3072
    __shared__ double red[256];
    int tid = threadIdx.x;
    double s = 0.0;
    for (int i = tid; i < n; i += 256) s += (double)partials[i];
    red[tid] = s;
    __syncthreads();
    for (int k = 128; k > 0; k >>= 1) {
        if (tid < k) red[tid] += red[tid + k];
        __syncthreads();
    }
    if (tid == 0) {
        double mean = red[0] / (double)((size_t)NBATCH * OUT_H * OUT_W);
        out[0] = (float)((1.0 - mean) * 0.5);
    }
}

extern "C" void kernel_launch(void* const* d_in, const int* in_sizes, int n_in,
                              void* d_out, int out_size, void* d_ws, size_t ws_size,
                              hipStream_t stream)
{
    const float* img1 = (const float*)d_in[0];
    const float* img2 = (const float*)d_in[1];
    float* out = (float*)d_out;
    float* partials = (float*)d_ws;  // 3072 floats = 12.3 KB

    dim3 grid(NSTRIPE, NCHUNK, NBATCH);  // 12 x 8 x 32 = 3072 blocks
    ssim_main<<<grid, dim3(64), 0, stream>>>(img1, img2, partials);
    ssim_reduce<<<1, dim3(256), 0, stream>>>(partials, out);
}